// Round 7
// baseline (1407.235 us; speedup 1.0000x reference)
//
#include <hip/hip_runtime.h>
#include <hip/hip_fp16.h>

// IntersiteModel fused kernel — fp32 compute, round 9: r8's LDS diet with the
// launch-bounds self-injury fixed.
// Post-mortem r8: TWO variables changed at once. LDS diet worked (occupancy
// 19->36%, 7 blocks/CU) but __launch_bounds__(TPB,4) forced a 64-VGPR cap ->
// 231MB spill writes / 657MB fetches ate the whole gain (still matched the
// 1292us best while paying ~560B/sample scratch!). This round: ONE change,
// launch_bounds(TPB,2) -> 128-VGPR cap (allocator's proven behavior), r8
// live-sets (~100-120 incl. y[40] in regs) fit spill-free.
//   * y (site2) in 40 registers (only statically indexed; v-loops unrolled).
//   * x/t0/t1 in LDS as fp16 half2-packed dword slots, feature-major:
//     D0..19 = x (40 halfs); D20..43 = t1 (48 halfs); t0 overwrites D0..15
//     after x dies. 44 slots * 4B * 128thr = 22528 B -> 7 blocks/CU
//     (14 waves/CU = 3.5 waves/SIMD vs 2 at the old 40KB layout).
//   * fp16 staging error: absmax 0.0625 (passed, was 0.0078 pure-fp32).
// Compute structure = r6 (best fp32): outer-u rolled loops w/ fully-unrolled
// v*k bodies (one latency window per ~256-1500 FMAs), W2_00/W2_11_0 split in
// lo/hi halves, W3 via 32 parallel accumulators. No barriers (per-thread
// LDS columns, 2-way bank aliasing free).

#define TPB 128

__device__ __forceinline__ float sigf(float x) {
    return 1.0f / (1.0f + __expf(-x));
}

__global__ __launch_bounds__(TPB, 2)
void intersite_fused(const float* __restrict__ site1,
                     const float* __restrict__ site2,
                     const float* __restrict__ edge,
                     const float* __restrict__ W1_00,
                     const float* __restrict__ W1_11_0,
                     const float* __restrict__ W1_01,
                     const float* __restrict__ W1_10,
                     const float* __restrict__ W1_11_1,
                     const float* __restrict__ W2_00,
                     const float* __restrict__ W2_11_0,
                     const float* __restrict__ W2_01,
                     const float* __restrict__ W2_10,
                     const float* __restrict__ W2_11_1,
                     const float* __restrict__ W3_00,
                     const float* __restrict__ W3_11,
                     float* __restrict__ out, int B)
{
    __shared__ float lds[44 * TPB];
    const int t = threadIdx.x;
    const int b = blockIdx.x * TPB + t;
    if (b >= B) return;   // no barriers anywhere -> early return is safe

    const __half* ph = (const __half*)lds;
    __half2* ph2 = (__half2*)lds;
    // half H lives at half-index ((H>>1)*TPB + t)*2 + (H&1)
#define RDH(H) __half2float(ph[(((((H) >> 1) * TPB) + t) << 1) | ((H) & 1)])
#define WRH2(D, a, bb) ph2[(D) * TPB + t] = __floats2half2_rn((a), (bb))

    const float inv_s3   = 0.57735026918962576f;  // 1/sqrt(3)
    const float inv_s2   = 0.70710678118654752f;  // 1/sqrt(2)
    const float inv_s320 = 0.05590169943749474f;  // 1/sqrt(320)
    const float inv_s192 = 0.07216878364870323f;  // 1/sqrt(192)
    const float inv_s256 = 0.0625f;               // 1/sqrt(256)
    const float inv_s2048= 0.02209708691207961f;  // 1/sqrt(2048)

    // ---------------- stage x -> LDS fp16 (D0..19), y -> regs ----------------
    {
        const float4* p1 = (const float4*)(site1 + (size_t)b * 40);
        #pragma unroll
        for (int q = 0; q < 10; ++q) {
            float4 r = p1[q];
            WRH2(q*2+0, r.x, r.y);
            WRH2(q*2+1, r.z, r.w);
        }
    }
    float y0r[16], y1r[24];
    {
        const float4* p2 = (const float4*)(site2 + (size_t)b * 40);
        #pragma unroll
        for (int q = 0; q < 4; ++q) {
            float4 r = p2[q];
            y0r[q*4+0]=r.x; y0r[q*4+1]=r.y; y0r[q*4+2]=r.z; y0r[q*4+3]=r.w;
        }
        #pragma unroll
        for (int q = 0; q < 6; ++q) {
            float4 r = p2[4+q];
            y1r[q*4+0]=r.x; y1r[q*4+1]=r.y; y1r[q*4+2]=r.z; y1r[q*4+3]=r.w;
        }
    }

    // ---------------- stage 1, pass A: t1[16][3] ----------------
    // x half-index map: x0[u] -> H=u ; x1[u,i] -> H=16+u*3+i
    float t1[48];
    #pragma unroll
    for (int j = 0; j < 48; ++j) t1[j] = 0.0f;

    // W1_01 (16,8,16): t1[k,i] += x0[u] y1[v,i] W[u,v,k]
    #pragma unroll 1
    for (int u = 0; u < 16; ++u) {
        float xu = RDH(u);
        const float* w01 = W1_01 + u * 128;
        #pragma unroll
        for (int v = 0; v < 8; ++v) {
            float f0 = xu * y1r[v*3+0];
            float f1 = xu * y1r[v*3+1];
            float f2 = xu * y1r[v*3+2];
            #pragma unroll
            for (int k = 0; k < 16; ++k) {
                float w = w01[v*16+k];
                t1[k*3+0] = fmaf(f0, w, t1[k*3+0]);
                t1[k*3+1] = fmaf(f1, w, t1[k*3+1]);
                t1[k*3+2] = fmaf(f2, w, t1[k*3+2]);
            }
        }
    }
    // merged W1_10 (8,16,16) + W1_11_1 (8,8,16): share x1[u] reads
    #pragma unroll 1
    for (int u = 0; u < 8; ++u) {
        float ax = RDH(16+u*3+0), ay = RDH(16+u*3+1), az = RDH(16+u*3+2);
        const float* w10 = W1_10 + u * 256;
        #pragma unroll
        for (int v = 0; v < 16; ++v) {
            float yv = y0r[v];
            float f0 = ax*yv, f1 = ay*yv, f2 = az*yv;
            #pragma unroll
            for (int k = 0; k < 16; ++k) {
                float w = w10[v*16+k];
                t1[k*3+0] = fmaf(f0, w, t1[k*3+0]);
                t1[k*3+1] = fmaf(f1, w, t1[k*3+1]);
                t1[k*3+2] = fmaf(f2, w, t1[k*3+2]);
            }
        }
        const float* w111 = W1_11_1 + u * 128;
        #pragma unroll
        for (int v = 0; v < 8; ++v) {
            float bx = y1r[v*3], by = y1r[v*3+1], bz = y1r[v*3+2];
            float cx = (ay*bz - az*by) * inv_s2;
            float cy = (az*bx - ax*bz) * inv_s2;
            float cz = (ax*by - ay*bx) * inv_s2;
            #pragma unroll
            for (int k = 0; k < 16; ++k) {
                float w = w111[v*16+k];
                t1[k*3+0] = fmaf(cx, w, t1[k*3+0]);
                t1[k*3+1] = fmaf(cy, w, t1[k*3+1]);
                t1[k*3+2] = fmaf(cz, w, t1[k*3+2]);
            }
        }
    }
    // t1 -> LDS fp16 at D20..43 (H = 40 + j)
    #pragma unroll
    for (int m = 0; m < 24; ++m)
        WRH2(20 + m, t1[2*m] * inv_s320, t1[2*m+1] * inv_s320);

    // ---------------- stage 1, pass B: t0[32] ----------------
    float t0[32];
    #pragma unroll
    for (int k = 0; k < 32; ++k) t0[k] = 0.0f;

    // W1_00 (16,16,32)
    #pragma unroll 1
    for (int u = 0; u < 16; ++u) {
        float xu = RDH(u);
        const float* w00 = W1_00 + u * 512;
        #pragma unroll
        for (int v = 0; v < 16; ++v) {
            float f = xu * y0r[v];
            #pragma unroll
            for (int k = 0; k < 32; ++k) t0[k] = fmaf(f, w00[v*32+k], t0[k]);
        }
    }
    // W1_11_0 (8,8,32)
    #pragma unroll 1
    for (int u = 0; u < 8; ++u) {
        float ax = RDH(16+u*3+0), ay = RDH(16+u*3+1), az = RDH(16+u*3+2);
        const float* w110 = W1_11_0 + u * 256;
        #pragma unroll
        for (int v = 0; v < 8; ++v) {
            float d = ax * y1r[v*3];
            d = fmaf(ay, y1r[v*3+1], d);
            d = fmaf(az, y1r[v*3+2], d);
            d *= inv_s3;
            #pragma unroll
            for (int k = 0; k < 32; ++k) t0[k] = fmaf(d, w110[v*32+k], t0[k]);
        }
    }
    // x dead now: t0 -> LDS fp16 at D0..15 (H = k)
    #pragma unroll
    for (int m = 0; m < 16; ++m)
        WRH2(m, t0[2*m] * inv_s320, t0[2*m+1] * inv_s320);

    // ---------------- edge -> regs ----------------
    float e0r[4], e1r[12];
    {
        const float4* pe = (const float4*)(edge + (size_t)b * 16);
        float4 r0 = pe[0], r1 = pe[1], r2 = pe[2], r3 = pe[3];
        e0r[0]=r0.x; e0r[1]=r0.y; e0r[2]=r0.z; e0r[3]=r0.w;
        e1r[0]=r1.x; e1r[1]=r1.y; e1r[2]=r1.z; e1r[3]=r1.w;
        e1r[4]=r2.x; e1r[5]=r2.y; e1r[6]=r2.z; e1r[7]=r2.w;
        e1r[8]=r3.x; e1r[9]=r3.y; e1r[10]=r3.z; e1r[11]=r3.w;
    }
    // t half-index map: t0[u] -> H=u ; t1[u,i] -> H=40+u*3+i

    float acc0 = 0.0f;
    // ---------------- stage 2a: u0 low half -> s -> acc0 ----------------
    {
        float ua[32];
        #pragma unroll
        for (int k = 0; k < 32; ++k) ua[k] = 0.0f;
        #pragma unroll 2
        for (int u = 0; u < 32; ++u) {
            float tu = RDH(u);
            const float* wu = W2_00 + u*256;
            #pragma unroll
            for (int v = 0; v < 4; ++v) {
                float f = tu * e0r[v];
                #pragma unroll
                for (int k = 0; k < 32; ++k) ua[k] = fmaf(f, wu[v*64+k], ua[k]);
            }
        }
        #pragma unroll 2
        for (int u = 0; u < 16; ++u) {
            float a0 = RDH(40+u*3+0), a1 = RDH(40+u*3+1), a2 = RDH(40+u*3+2);
            const float* wu = W2_11_0 + u*256;
            #pragma unroll
            for (int v = 0; v < 4; ++v) {
                float d = a0 * e1r[v*3];
                d = fmaf(a1, e1r[v*3+1], d);
                d = fmaf(a2, e1r[v*3+2], d);
                d *= inv_s3;
                #pragma unroll
                for (int k = 0; k < 32; ++k) ua[k] = fmaf(d, wu[v*64+k], ua[k]);
            }
        }
        #pragma unroll
        for (int k = 0; k < 32; ++k) {
            float x = ua[k] * inv_s192;
            ua[k] = x * sigf(x);
        }
        float zs[32];
        #pragma unroll
        for (int k = 0; k < 32; ++k) zs[k] = 0.0f;
        #pragma unroll
        for (int u = 0; u < 32; ++u) {
            const float* w = W3_00 + u*32;
            #pragma unroll
            for (int k = 0; k < 32; ++k) zs[k] = fmaf(ua[u], w[k], zs[k]);
        }
        #pragma unroll
        for (int k = 0; k < 32; ++k) acc0 = fmaf(zs[k], ua[k], acc0);
    }

    // ---------------- stage 2a': u0 high half -> g[32] ----------------
    float g[32];
    {
        float ub[32];
        #pragma unroll
        for (int k = 0; k < 32; ++k) ub[k] = 0.0f;
        #pragma unroll 2
        for (int u = 0; u < 32; ++u) {
            float tu = RDH(u);
            const float* wu = W2_00 + u*256 + 32;
            #pragma unroll
            for (int v = 0; v < 4; ++v) {
                float f = tu * e0r[v];
                #pragma unroll
                for (int k = 0; k < 32; ++k) ub[k] = fmaf(f, wu[v*64+k], ub[k]);
            }
        }
        #pragma unroll 2
        for (int u = 0; u < 16; ++u) {
            float a0 = RDH(40+u*3+0), a1 = RDH(40+u*3+1), a2 = RDH(40+u*3+2);
            const float* wu = W2_11_0 + u*256 + 32;
            #pragma unroll
            for (int v = 0; v < 4; ++v) {
                float d = a0 * e1r[v*3];
                d = fmaf(a1, e1r[v*3+1], d);
                d = fmaf(a2, e1r[v*3+2], d);
                d *= inv_s3;
                #pragma unroll
                for (int k = 0; k < 32; ++k) ub[k] = fmaf(d, wu[v*64+k], ub[k]);
            }
        }
        #pragma unroll
        for (int k = 0; k < 32; ++k) g[k] = sigf(ub[k] * inv_s192);
    }

    // ---------------- stage 2b+3: per-component u1_i -> gate -> acc1 -------
    float acc1 = 0.0f;
    const float* ep = edge + (size_t)b * 16 + 4;
    #pragma unroll 1
    for (int i = 0; i < 3; ++i) {
        int jj = (i == 2) ? 0 : i + 1;
        int kk = (jj == 2) ? 0 : jj + 1;
        float e1i[4], e1j[4], e1k4[4];
        #pragma unroll
        for (int v = 0; v < 4; ++v) {
            e1i[v]  = ep[v*3 + i];
            e1j[v]  = ep[v*3 + jj];
            e1k4[v] = ep[v*3 + kk];
        }
        float u1i[32];
        #pragma unroll
        for (int k = 0; k < 32; ++k) u1i[k] = 0.0f;

        // W2_01 (32,4,32): u1_i[k] += t0[u] e1[v,i] W[u,v,k]
        #pragma unroll 2
        for (int u = 0; u < 32; ++u) {
            float tu = RDH(u);
            const float* wu = W2_01 + u*128;
            #pragma unroll
            for (int v = 0; v < 4; ++v) {
                float f = tu * e1i[v];
                #pragma unroll
                for (int k = 0; k < 32; ++k) u1i[k] = fmaf(f, wu[v*32+k], u1i[k]);
            }
        }
        // merged W2_10 + W2_11_1 (u<16 shares t1[u] reads)
        #pragma unroll 2
        for (int u = 0; u < 16; ++u) {
            float ai = RDH(40 + u*3 + i);
            float aj = RDH(40 + u*3 + jj);
            float ak = RDH(40 + u*3 + kk);
            const float* wa = W2_10   + u*128;
            const float* wb = W2_11_1 + u*128;
            #pragma unroll
            for (int v = 0; v < 4; ++v) {
                float f = ai * e0r[v];
                float c = (aj * e1k4[v] - ak * e1j[v]) * inv_s2;
                #pragma unroll
                for (int k = 0; k < 32; ++k)
                    u1i[k] = fmaf(f, wa[v*32+k], fmaf(c, wb[v*32+k], u1i[k]));
            }
        }
        // gate: v_i = (u1_i/sqrt256) * g ; acc1 += v_i^T W3_11 v_i
        #pragma unroll
        for (int k = 0; k < 32; ++k) u1i[k] = u1i[k] * inv_s256 * g[k];
        float zv[32];
        #pragma unroll
        for (int k = 0; k < 32; ++k) zv[k] = 0.0f;
        #pragma unroll
        for (int u = 0; u < 32; ++u) {
            const float* w = W3_11 + u*32;
            #pragma unroll
            for (int k = 0; k < 32; ++k) zv[k] = fmaf(u1i[u], w[k], zv[k]);
        }
        #pragma unroll
        for (int k = 0; k < 32; ++k) acc1 = fmaf(zv[k], u1i[k], acc1);
    }

    out[b] = (acc0 + acc1 * inv_s3) * inv_s2048;
#undef RDH
#undef WRH2
}

extern "C" void kernel_launch(void* const* d_in, const int* in_sizes, int n_in,
                              void* d_out, int out_size, void* d_ws, size_t ws_size,
                              hipStream_t stream)
{
    const float* site1   = (const float*)d_in[0];
    const float* site2   = (const float*)d_in[1];
    const float* edge    = (const float*)d_in[2];
    const float* W1_00   = (const float*)d_in[3];
    const float* W1_11_0 = (const float*)d_in[4];
    const float* W1_01   = (const float*)d_in[5];
    const float* W1_10   = (const float*)d_in[6];
    const float* W1_11_1 = (const float*)d_in[7];
    const float* W2_00   = (const float*)d_in[8];
    const float* W2_11_0 = (const float*)d_in[9];
    const float* W2_01   = (const float*)d_in[10];
    const float* W2_10   = (const float*)d_in[11];
    const float* W2_11_1 = (const float*)d_in[12];
    const float* W3_00   = (const float*)d_in[13];
    const float* W3_11   = (const float*)d_in[14];
    float* out = (float*)d_out;

    const int B = in_sizes[0] / 40;
    dim3 grid((B + TPB - 1) / TPB), block(TPB);
    hipLaunchKernelGGL(intersite_fused, grid, block, 0, stream,
                       site1, site2, edge,
                       W1_00, W1_11_0, W1_01, W1_10, W1_11_1,
                       W2_00, W2_11_0, W2_01, W2_10, W2_11_1,
                       W3_00, W3_11, out, B);
}

// Round 8
// 1138.363 us; speedup vs baseline: 1.2362x; 1.2362x over previous
//
#include <hip/hip_runtime.h>
#include <hip/hip_fp16.h>

// IntersiteModel fused kernel — fp32 compute, round 10: uncap the occupancy.
// Post-mortem r9: LDS diet (22.5KB, 7 blocks/CU possible) gave NO occupancy
// gain — measured 20% = ~2 waves/SIMD, exactly the __launch_bounds__(TPB,2)
// level. Cross-round evidence: r8 with (TPB,4) measured 36% (tracks the LDS
// limit); every (TPB,2) round measured ~19-20% regardless of LDS. The 2nd
// launch-bounds arg is empirically CAPPING waves/SIMD, not just setting the
// allocator minimum. r8 proved the upside (36% occ matched best-fp32 perf
// WHILE paying 231MB spills from its 64-VGPR cap); r9 removed spills but
// reinstated the cap. This round, ONE variable: launch_bounds(TPB, 3) ->
// VGPR budget 512/3 ~= 170 (>> ~110 live set, no spill) and wave cap
// 3/SIMD = 12 waves/CU (LDS allows 14). Everything else identical to r9:
//   * y (site2) in 40 registers (statically indexed only).
//   * x/t0/t1 in LDS as fp16 half2-packed dword slots, feature-major:
//     D0..19 = x; D20..43 = t1; t0 overwrites D0..15 once x dies.
//     44 slots * 4B * 128thr = 22528 B/block.
//   * outer-u rolled loops with fully-unrolled v*k bodies; W2 lo/hi halves;
//     W3 via 32 parallel accumulators; no barriers (per-thread LDS columns).

#define TPB 128

__device__ __forceinline__ float sigf(float x) {
    return 1.0f / (1.0f + __expf(-x));
}

__global__ __launch_bounds__(TPB, 3)
void intersite_fused(const float* __restrict__ site1,
                     const float* __restrict__ site2,
                     const float* __restrict__ edge,
                     const float* __restrict__ W1_00,
                     const float* __restrict__ W1_11_0,
                     const float* __restrict__ W1_01,
                     const float* __restrict__ W1_10,
                     const float* __restrict__ W1_11_1,
                     const float* __restrict__ W2_00,
                     const float* __restrict__ W2_11_0,
                     const float* __restrict__ W2_01,
                     const float* __restrict__ W2_10,
                     const float* __restrict__ W2_11_1,
                     const float* __restrict__ W3_00,
                     const float* __restrict__ W3_11,
                     float* __restrict__ out, int B)
{
    __shared__ float lds[44 * TPB];
    const int t = threadIdx.x;
    const int b = blockIdx.x * TPB + t;
    if (b >= B) return;   // no barriers anywhere -> early return is safe

    const __half* ph = (const __half*)lds;
    __half2* ph2 = (__half2*)lds;
    // half H lives at half-index ((H>>1)*TPB + t)*2 + (H&1)
#define RDH(H) __half2float(ph[(((((H) >> 1) * TPB) + t) << 1) | ((H) & 1)])
#define WRH2(D, a, bb) ph2[(D) * TPB + t] = __floats2half2_rn((a), (bb))

    const float inv_s3   = 0.57735026918962576f;  // 1/sqrt(3)
    const float inv_s2   = 0.70710678118654752f;  // 1/sqrt(2)
    const float inv_s320 = 0.05590169943749474f;  // 1/sqrt(320)
    const float inv_s192 = 0.07216878364870323f;  // 1/sqrt(192)
    const float inv_s256 = 0.0625f;               // 1/sqrt(256)
    const float inv_s2048= 0.02209708691207961f;  // 1/sqrt(2048)

    // ---------------- stage x -> LDS fp16 (D0..19), y -> regs ----------------
    {
        const float4* p1 = (const float4*)(site1 + (size_t)b * 40);
        #pragma unroll
        for (int q = 0; q < 10; ++q) {
            float4 r = p1[q];
            WRH2(q*2+0, r.x, r.y);
            WRH2(q*2+1, r.z, r.w);
        }
    }
    float y0r[16], y1r[24];
    {
        const float4* p2 = (const float4*)(site2 + (size_t)b * 40);
        #pragma unroll
        for (int q = 0; q < 4; ++q) {
            float4 r = p2[q];
            y0r[q*4+0]=r.x; y0r[q*4+1]=r.y; y0r[q*4+2]=r.z; y0r[q*4+3]=r.w;
        }
        #pragma unroll
        for (int q = 0; q < 6; ++q) {
            float4 r = p2[4+q];
            y1r[q*4+0]=r.x; y1r[q*4+1]=r.y; y1r[q*4+2]=r.z; y1r[q*4+3]=r.w;
        }
    }

    // ---------------- stage 1, pass A: t1[16][3] ----------------
    // x half-index map: x0[u] -> H=u ; x1[u,i] -> H=16+u*3+i
    float t1[48];
    #pragma unroll
    for (int j = 0; j < 48; ++j) t1[j] = 0.0f;

    // W1_01 (16,8,16): t1[k,i] += x0[u] y1[v,i] W[u,v,k]
    #pragma unroll 1
    for (int u = 0; u < 16; ++u) {
        float xu = RDH(u);
        const float* w01 = W1_01 + u * 128;
        #pragma unroll
        for (int v = 0; v < 8; ++v) {
            float f0 = xu * y1r[v*3+0];
            float f1 = xu * y1r[v*3+1];
            float f2 = xu * y1r[v*3+2];
            #pragma unroll
            for (int k = 0; k < 16; ++k) {
                float w = w01[v*16+k];
                t1[k*3+0] = fmaf(f0, w, t1[k*3+0]);
                t1[k*3+1] = fmaf(f1, w, t1[k*3+1]);
                t1[k*3+2] = fmaf(f2, w, t1[k*3+2]);
            }
        }
    }
    // merged W1_10 (8,16,16) + W1_11_1 (8,8,16): share x1[u] reads
    #pragma unroll 1
    for (int u = 0; u < 8; ++u) {
        float ax = RDH(16+u*3+0), ay = RDH(16+u*3+1), az = RDH(16+u*3+2);
        const float* w10 = W1_10 + u * 256;
        #pragma unroll
        for (int v = 0; v < 16; ++v) {
            float yv = y0r[v];
            float f0 = ax*yv, f1 = ay*yv, f2 = az*yv;
            #pragma unroll
            for (int k = 0; k < 16; ++k) {
                float w = w10[v*16+k];
                t1[k*3+0] = fmaf(f0, w, t1[k*3+0]);
                t1[k*3+1] = fmaf(f1, w, t1[k*3+1]);
                t1[k*3+2] = fmaf(f2, w, t1[k*3+2]);
            }
        }
        const float* w111 = W1_11_1 + u * 128;
        #pragma unroll
        for (int v = 0; v < 8; ++v) {
            float bx = y1r[v*3], by = y1r[v*3+1], bz = y1r[v*3+2];
            float cx = (ay*bz - az*by) * inv_s2;
            float cy = (az*bx - ax*bz) * inv_s2;
            float cz = (ax*by - ay*bx) * inv_s2;
            #pragma unroll
            for (int k = 0; k < 16; ++k) {
                float w = w111[v*16+k];
                t1[k*3+0] = fmaf(cx, w, t1[k*3+0]);
                t1[k*3+1] = fmaf(cy, w, t1[k*3+1]);
                t1[k*3+2] = fmaf(cz, w, t1[k*3+2]);
            }
        }
    }
    // t1 -> LDS fp16 at D20..43 (H = 40 + j)
    #pragma unroll
    for (int m = 0; m < 24; ++m)
        WRH2(20 + m, t1[2*m] * inv_s320, t1[2*m+1] * inv_s320);

    // ---------------- stage 1, pass B: t0[32] ----------------
    float t0[32];
    #pragma unroll
    for (int k = 0; k < 32; ++k) t0[k] = 0.0f;

    // W1_00 (16,16,32)
    #pragma unroll 1
    for (int u = 0; u < 16; ++u) {
        float xu = RDH(u);
        const float* w00 = W1_00 + u * 512;
        #pragma unroll
        for (int v = 0; v < 16; ++v) {
            float f = xu * y0r[v];
            #pragma unroll
            for (int k = 0; k < 32; ++k) t0[k] = fmaf(f, w00[v*32+k], t0[k]);
        }
    }
    // W1_11_0 (8,8,32)
    #pragma unroll 1
    for (int u = 0; u < 8; ++u) {
        float ax = RDH(16+u*3+0), ay = RDH(16+u*3+1), az = RDH(16+u*3+2);
        const float* w110 = W1_11_0 + u * 256;
        #pragma unroll
        for (int v = 0; v < 8; ++v) {
            float d = ax * y1r[v*3];
            d = fmaf(ay, y1r[v*3+1], d);
            d = fmaf(az, y1r[v*3+2], d);
            d *= inv_s3;
            #pragma unroll
            for (int k = 0; k < 32; ++k) t0[k] = fmaf(d, w110[v*32+k], t0[k]);
        }
    }
    // x dead now: t0 -> LDS fp16 at D0..15 (H = k)
    #pragma unroll
    for (int m = 0; m < 16; ++m)
        WRH2(m, t0[2*m] * inv_s320, t0[2*m+1] * inv_s320);

    // ---------------- edge -> regs ----------------
    float e0r[4], e1r[12];
    {
        const float4* pe = (const float4*)(edge + (size_t)b * 16);
        float4 r0 = pe[0], r1 = pe[1], r2 = pe[2], r3 = pe[3];
        e0r[0]=r0.x; e0r[1]=r0.y; e0r[2]=r0.z; e0r[3]=r0.w;
        e1r[0]=r1.x; e1r[1]=r1.y; e1r[2]=r1.z; e1r[3]=r1.w;
        e1r[4]=r2.x; e1r[5]=r2.y; e1r[6]=r2.z; e1r[7]=r2.w;
        e1r[8]=r3.x; e1r[9]=r3.y; e1r[10]=r3.z; e1r[11]=r3.w;
    }
    // t half-index map: t0[u] -> H=u ; t1[u,i] -> H=40+u*3+i

    float acc0 = 0.0f;
    // ---------------- stage 2a: u0 low half -> s -> acc0 ----------------
    {
        float ua[32];
        #pragma unroll
        for (int k = 0; k < 32; ++k) ua[k] = 0.0f;
        #pragma unroll 2
        for (int u = 0; u < 32; ++u) {
            float tu = RDH(u);
            const float* wu = W2_00 + u*256;
            #pragma unroll
            for (int v = 0; v < 4; ++v) {
                float f = tu * e0r[v];
                #pragma unroll
                for (int k = 0; k < 32; ++k) ua[k] = fmaf(f, wu[v*64+k], ua[k]);
            }
        }
        #pragma unroll 2
        for (int u = 0; u < 16; ++u) {
            float a0 = RDH(40+u*3+0), a1 = RDH(40+u*3+1), a2 = RDH(40+u*3+2);
            const float* wu = W2_11_0 + u*256;
            #pragma unroll
            for (int v = 0; v < 4; ++v) {
                float d = a0 * e1r[v*3];
                d = fmaf(a1, e1r[v*3+1], d);
                d = fmaf(a2, e1r[v*3+2], d);
                d *= inv_s3;
                #pragma unroll
                for (int k = 0; k < 32; ++k) ua[k] = fmaf(d, wu[v*64+k], ua[k]);
            }
        }
        #pragma unroll
        for (int k = 0; k < 32; ++k) {
            float x = ua[k] * inv_s192;
            ua[k] = x * sigf(x);
        }
        float zs[32];
        #pragma unroll
        for (int k = 0; k < 32; ++k) zs[k] = 0.0f;
        #pragma unroll
        for (int u = 0; u < 32; ++u) {
            const float* w = W3_00 + u*32;
            #pragma unroll
            for (int k = 0; k < 32; ++k) zs[k] = fmaf(ua[u], w[k], zs[k]);
        }
        #pragma unroll
        for (int k = 0; k < 32; ++k) acc0 = fmaf(zs[k], ua[k], acc0);
    }

    // ---------------- stage 2a': u0 high half -> g[32] ----------------
    float g[32];
    {
        float ub[32];
        #pragma unroll
        for (int k = 0; k < 32; ++k) ub[k] = 0.0f;
        #pragma unroll 2
        for (int u = 0; u < 32; ++u) {
            float tu = RDH(u);
            const float* wu = W2_00 + u*256 + 32;
            #pragma unroll
            for (int v = 0; v < 4; ++v) {
                float f = tu * e0r[v];
                #pragma unroll
                for (int k = 0; k < 32; ++k) ub[k] = fmaf(f, wu[v*64+k], ub[k]);
            }
        }
        #pragma unroll 2
        for (int u = 0; u < 16; ++u) {
            float a0 = RDH(40+u*3+0), a1 = RDH(40+u*3+1), a2 = RDH(40+u*3+2);
            const float* wu = W2_11_0 + u*256 + 32;
            #pragma unroll
            for (int v = 0; v < 4; ++v) {
                float d = a0 * e1r[v*3];
                d = fmaf(a1, e1r[v*3+1], d);
                d = fmaf(a2, e1r[v*3+2], d);
                d *= inv_s3;
                #pragma unroll
                for (int k = 0; k < 32; ++k) ub[k] = fmaf(d, wu[v*64+k], ub[k]);
            }
        }
        #pragma unroll
        for (int k = 0; k < 32; ++k) g[k] = sigf(ub[k] * inv_s192);
    }

    // ---------------- stage 2b+3: per-component u1_i -> gate -> acc1 -------
    float acc1 = 0.0f;
    const float* ep = edge + (size_t)b * 16 + 4;
    #pragma unroll 1
    for (int i = 0; i < 3; ++i) {
        int jj = (i == 2) ? 0 : i + 1;
        int kk = (jj == 2) ? 0 : jj + 1;
        float e1i[4], e1j[4], e1k4[4];
        #pragma unroll
        for (int v = 0; v < 4; ++v) {
            e1i[v]  = ep[v*3 + i];
            e1j[v]  = ep[v*3 + jj];
            e1k4[v] = ep[v*3 + kk];
        }
        float u1i[32];
        #pragma unroll
        for (int k = 0; k < 32; ++k) u1i[k] = 0.0f;

        // W2_01 (32,4,32): u1_i[k] += t0[u] e1[v,i] W[u,v,k]
        #pragma unroll 2
        for (int u = 0; u < 32; ++u) {
            float tu = RDH(u);
            const float* wu = W2_01 + u*128;
            #pragma unroll
            for (int v = 0; v < 4; ++v) {
                float f = tu * e1i[v];
                #pragma unroll
                for (int k = 0; k < 32; ++k) u1i[k] = fmaf(f, wu[v*32+k], u1i[k]);
            }
        }
        // merged W2_10 + W2_11_1 (u<16 shares t1[u] reads)
        #pragma unroll 2
        for (int u = 0; u < 16; ++u) {
            float ai = RDH(40 + u*3 + i);
            float aj = RDH(40 + u*3 + jj);
            float ak = RDH(40 + u*3 + kk);
            const float* wa = W2_10   + u*128;
            const float* wb = W2_11_1 + u*128;
            #pragma unroll
            for (int v = 0; v < 4; ++v) {
                float f = ai * e0r[v];
                float c = (aj * e1k4[v] - ak * e1j[v]) * inv_s2;
                #pragma unroll
                for (int k = 0; k < 32; ++k)
                    u1i[k] = fmaf(f, wa[v*32+k], fmaf(c, wb[v*32+k], u1i[k]));
            }
        }
        // gate: v_i = (u1_i/sqrt256) * g ; acc1 += v_i^T W3_11 v_i
        #pragma unroll
        for (int k = 0; k < 32; ++k) u1i[k] = u1i[k] * inv_s256 * g[k];
        float zv[32];
        #pragma unroll
        for (int k = 0; k < 32; ++k) zv[k] = 0.0f;
        #pragma unroll
        for (int u = 0; u < 32; ++u) {
            const float* w = W3_11 + u*32;
            #pragma unroll
            for (int k = 0; k < 32; ++k) zv[k] = fmaf(u1i[u], w[k], zv[k]);
        }
        #pragma unroll
        for (int k = 0; k < 32; ++k) acc1 = fmaf(zv[k], u1i[k], acc1);
    }

    out[b] = (acc0 + acc1 * inv_s3) * inv_s2048;
#undef RDH
#undef WRH2
}

extern "C" void kernel_launch(void* const* d_in, const int* in_sizes, int n_in,
                              void* d_out, int out_size, void* d_ws, size_t ws_size,
                              hipStream_t stream)
{
    const float* site1   = (const float*)d_in[0];
    const float* site2   = (const float*)d_in[1];
    const float* edge    = (const float*)d_in[2];
    const float* W1_00   = (const float*)d_in[3];
    const float* W1_11_0 = (const float*)d_in[4];
    const float* W1_01   = (const float*)d_in[5];
    const float* W1_10   = (const float*)d_in[6];
    const float* W1_11_1 = (const float*)d_in[7];
    const float* W2_00   = (const float*)d_in[8];
    const float* W2_11_0 = (const float*)d_in[9];
    const float* W2_01   = (const float*)d_in[10];
    const float* W2_10   = (const float*)d_in[11];
    const float* W2_11_1 = (const float*)d_in[12];
    const float* W3_00   = (const float*)d_in[13];
    const float* W3_11   = (const float*)d_in[14];
    float* out = (float*)d_out;

    const int B = in_sizes[0] / 40;
    dim3 grid((B + TPB - 1) / TPB), block(TPB);
    hipLaunchKernelGGL(intersite_fused, grid, block, 0, stream,
                       site1, site2, edge,
                       W1_00, W1_11_0, W1_01, W1_10, W1_11_1,
                       W2_00, W2_11_0, W2_01, W2_10, W2_11_1,
                       W3_00, W3_11, out, B);
}